// Round 10
// baseline (124.425 us; speedup 1.0000x reference)
//
#include <hip/hip_runtime.h>
#include <hip/hip_bf16.h>
#include <cstdint>
#include <cstddef>
#include <math.h>

#define D 256
#define TEMP_INV 2.0f       // 1 / TEMPERATURE, TEMPERATURE = 0.5
#define EPS_NORM 1e-8f
#define NSUP 1056           // sum_{y=0..31} (64-2y) 256x128 supertiles

typedef __attribute__((ext_vector_type(8))) short bf16x8;
typedef __attribute__((ext_vector_type(4))) float f32x4;

// ---------------- kernel 1: normalize rows, write bf16 zn ----------------
__global__ void __launch_bounds__(256) normalize_rows(
    const float* __restrict__ zi, const float* __restrict__ zj,
    __hip_bfloat16* __restrict__ zn, float* __restrict__ denom,
    unsigned* __restrict__ counter, int B) {
  const int wid = threadIdx.x >> 6;
  const int lane = threadIdx.x & 63;
  if (threadIdx.x < 16) denom[blockIdx.x * 16 + threadIdx.x] = 0.0f;
  if (blockIdx.x == 0 && threadIdx.x == 0) *counter = 0u;
#pragma unroll
  for (int it = 0; it < 4; ++it) {
    int row = it * 2048 + blockIdx.x * 4 + wid;
    const float* src = (row < B) ? (zi + (size_t)row * D)
                                 : (zj + (size_t)(row - B) * D);
    float4 v = ((const float4*)src)[lane];
    float ss = v.x * v.x + v.y * v.y + v.z * v.z + v.w * v.w;
    for (int off = 32; off; off >>= 1) ss += __shfl_xor(ss, off);
    float rn = 1.0f / fmaxf(sqrtf(ss), EPS_NORM);
    union { ushort4 u; __hip_bfloat16 h[4]; } o;
    o.h[0] = __float2bfloat16(v.x * rn);
    o.h[1] = __float2bfloat16(v.y * rn);
    o.h[2] = __float2bfloat16(v.z * rn);
    o.h[3] = __float2bfloat16(v.w * rn);
    ((ushort4*)zn)[(size_t)row * (D / 4) + lane] = o.u;
  }
}

// ---------------- kernel 2: supertile GEMM + epilogue + last-block loss --
// 256x128 supertile per block (two stacked 128-tiles share the B staging,
// doubling MFMA per latency chain vs R8). Upper-tri enumeration:
// by2 in [0,32), bx in [2*by2, 64). Half-tile modes: bx==2by2 -> top half
// is the diagonal tile (rs only, mask r==c), bottom half below diagonal
// (skip); bx==2by2+1 -> bottom half is the diagonal tile; else normal
// (rs + cs). Staging: lane-sequential coalesced float4 loads (R8-proven)
// -> ds_write with XOR swizzle on LDS addr (0 conflicts R4/R6-R8), named
// scalars only (no aggregates live across barriers). Finalize runs in the
// last block to finish (threadfence + ticket), killing one launch.
__device__ __forceinline__ void decode_supertile(int t, int& by2, int& bx) {
  // C(y) = y*(65-y) supertiles before row y
  int y = (int)((65.0f - sqrtf(4225.0f - 4.0f * (float)t)) * 0.5f);
  while ((y + 1) * (65 - (y + 1)) <= t) ++y;
  while (y * (65 - y) > t) --y;
  by2 = y;
  bx = 2 * y + (t - y * (65 - y));
}

__global__ void __launch_bounds__(256, 2) ntxent_gemm(
    const __hip_bfloat16* __restrict__ zn, float* __restrict__ denom,
    float* __restrict__ pos, unsigned* __restrict__ counter,
    float* __restrict__ out, int B) {
  __shared__ __align__(16) __hip_bfloat16 Ash[256 * 64];  // 32 KB
  __shared__ __align__(16) __hip_bfloat16 Bsh[128 * 64];  // 16 KB
  __shared__ unsigned ticket_s;
  __shared__ float red_s[4];

  const int N = 2 * B;
  int by2, bx;
  decode_supertile(blockIdx.x, by2, bx);
  const int bm = by2 * 256;
  const int bn = bx * 128;
  const bool stDiag0 = (bx == 2 * by2);
  const bool stDiag1 = (bx == 2 * by2 + 1);

  const int tid = threadIdx.x;
  const int wid = tid >> 6;
  const int lane = tid & 63;
  const bool topHalf = (wid < 2);
  const bool waveSkip = stDiag0 && !topHalf;                       // below diag
  const bool diagMode = (stDiag0 && topHalf) || (stDiag1 && !topHalf);
  const bool isPosST = ((bn - bm) == B) || ((bn - bm) == B + 128);

  const int wrow0A = wid * 64;   // wave's 64 A-rows within supertile
  const int wrow0B = wid * 32;   // wave's 32 staged B-rows
  const int lr = lane >> 3;      // staging row within 8-row group (== r&7)
  const int c8 = lane & 7;       // 16B chunk, SEQUENTIAL in global memory
  const int frow = lane & 15;
  const int quad = lane >> 4;
  const int f7 = frow & 7;

  f32x4 acc[4][8] = {};

  const __hip_bfloat16* gA = zn + (size_t)(bm + wrow0A + lr) * D + c8 * 8;
  const __hip_bfloat16* gB = zn + (size_t)(bn + wrow0B + lr) * D + c8 * 8;
  const int loffA = (wrow0A + lr) * 64 + (c8 ^ lr) * 8;
  const int loffB = (wrow0B + lr) * 64 + (c8 ^ lr) * 8;

#pragma unroll
  for (int k0i = 0; k0i < 4; ++k0i) {
    const int k0 = k0i * 64;
    // coalesced loads; named scalars, in-iteration lifetime (no-spill shape)
    float4 a0 = *(const float4*)(gA + 0 * 8 * D + k0);
    float4 a1 = *(const float4*)(gA + 1 * 8 * D + k0);
    float4 a2 = *(const float4*)(gA + 2 * 8 * D + k0);
    float4 a3 = *(const float4*)(gA + 3 * 8 * D + k0);
    float4 a4 = *(const float4*)(gA + 4 * 8 * D + k0);
    float4 a5 = *(const float4*)(gA + 5 * 8 * D + k0);
    float4 a6 = *(const float4*)(gA + 6 * 8 * D + k0);
    float4 a7 = *(const float4*)(gA + 7 * 8 * D + k0);
    float4 b0 = *(const float4*)(gB + 0 * 8 * D + k0);
    float4 b1 = *(const float4*)(gB + 1 * 8 * D + k0);
    float4 b2 = *(const float4*)(gB + 2 * 8 * D + k0);
    float4 b3 = *(const float4*)(gB + 3 * 8 * D + k0);
    __syncthreads();  // WAR: previous slab's LDS reads complete
    *(float4*)&Ash[loffA + 0 * 8 * 64] = a0;
    *(float4*)&Ash[loffA + 1 * 8 * 64] = a1;
    *(float4*)&Ash[loffA + 2 * 8 * 64] = a2;
    *(float4*)&Ash[loffA + 3 * 8 * 64] = a3;
    *(float4*)&Ash[loffA + 4 * 8 * 64] = a4;
    *(float4*)&Ash[loffA + 5 * 8 * 64] = a5;
    *(float4*)&Ash[loffA + 6 * 8 * 64] = a6;
    *(float4*)&Ash[loffA + 7 * 8 * 64] = a7;
    *(float4*)&Bsh[loffB + 0 * 8 * 64] = b0;
    *(float4*)&Bsh[loffB + 1 * 8 * 64] = b1;
    *(float4*)&Bsh[loffB + 2 * 8 * 64] = b2;
    *(float4*)&Bsh[loffB + 3 * 8 * 64] = b3;
    __syncthreads();
    if (!waveSkip) {
#pragma unroll
      for (int kk = 0; kk < 2; ++kk) {
        bf16x8 af[4], bf[8];
#pragma unroll
        for (int i = 0; i < 4; ++i)
          af[i] = *(const bf16x8*)
              &Ash[(wrow0A + i * 16 + frow) * 64 + ((kk * 4 + quad) ^ f7) * 8];
#pragma unroll
        for (int j = 0; j < 8; ++j)
          bf[j] = *(const bf16x8*)
              &Bsh[(j * 16 + frow) * 64 + ((kk * 4 + quad) ^ f7) * 8];
#pragma unroll
        for (int i = 0; i < 4; ++i)
#pragma unroll
          for (int j = 0; j < 8; ++j)
            acc[i][j] = __builtin_amdgcn_mfma_f32_16x16x32_bf16(
                af[i], bf[j], acc[i][j], 0, 0, 0);
      }
    }
  }

  // epilogue: C/D layout col = lane&15, row = quad*4 + reg
  if (!waveSkip) {
    const int colq = frow;
    float cs[8] = {};
#pragma unroll
    for (int i = 0; i < 4; ++i) {
#pragma unroll
      for (int r = 0; r < 4; ++r) {
        int row = bm + wrow0A + i * 16 + quad * 4 + r;
        float rs = 0.0f;
#pragma unroll
        for (int j = 0; j < 8; ++j) {
          int col = bn + j * 16 + colq;
          float v = acc[i][j][r];
          float e = __expf(v * TEMP_INV);
          e = (diagMode && col == row) ? 0.0f : e;
          rs += e;
          cs[j] += e;
          if (isPosST && col == row + B) { pos[row] = v; pos[col] = v; }
        }
        rs += __shfl_xor(rs, 1);
        rs += __shfl_xor(rs, 2);
        rs += __shfl_xor(rs, 4);
        rs += __shfl_xor(rs, 8);
        if (colq == 0) atomicAdd(&denom[row], rs);
      }
    }
    if (!diagMode) {
#pragma unroll
      for (int j = 0; j < 8; ++j) {
        float c = cs[j];
        c += __shfl_xor(c, 16);
        c += __shfl_xor(c, 32);
        if (quad == 0) atomicAdd(&denom[bn + j * 16 + colq], c);
      }
    }
  }

  // -------- last block to finish computes the loss (device-scope fence) --
  __syncthreads();  // all waves' stores/atomics drained (waitcnt at barrier)
  if (tid == 0) {
    __threadfence();                      // release: publish pos/denom
    ticket_s = atomicAdd(counter, 1u);
  }
  __syncthreads();
  if (ticket_s == NSUP - 1) {
    __threadfence();                      // acquire: see all blocks' writes
    float s = 0.0f;
    for (int i = tid; i < N / 4; i += 256) {
      float4 d = ((const float4*)denom)[i];
      float4 p = ((const float4*)pos)[i];
      s += __logf(d.x) - p.x * TEMP_INV;
      s += __logf(d.y) - p.y * TEMP_INV;
      s += __logf(d.z) - p.z * TEMP_INV;
      s += __logf(d.w) - p.w * TEMP_INV;
    }
    for (int off = 32; off; off >>= 1) s += __shfl_xor(s, off);
    if (lane == 0) red_s[wid] = s;
    __syncthreads();
    if (tid == 0)
      out[0] = (red_s[0] + red_s[1] + red_s[2] + red_s[3]) / (float)N;
  }
}

extern "C" void kernel_launch(void* const* d_in, const int* in_sizes, int n_in,
                              void* d_out, int out_size, void* d_ws, size_t ws_size,
                              hipStream_t stream) {
  const float* zi = (const float*)d_in[0];
  const float* zj = (const float*)d_in[1];
  const int B = in_sizes[0] / D;  // 4096
  const int N = 2 * B;            // 8192

  __hip_bfloat16* zn = (__hip_bfloat16*)d_ws;
  float* denom = (float*)((char*)d_ws + (size_t)N * D * sizeof(__hip_bfloat16));
  float* pos = denom + N;
  unsigned* counter = (unsigned*)(pos + N);

  normalize_rows<<<512, 256, 0, stream>>>(zi, zj, zn, denom, counter, B);
  ntxent_gemm<<<NSUP, 256, 0, stream>>>(zn, denom, pos, counter,
                                        (float*)d_out, B);
}